// Round 1
// baseline (1804.338 us; speedup 1.0000x reference)
//
#include <hip/hip_runtime.h>
#include <stdint.h>

// ---------------- types ----------------
typedef short bf16x8 __attribute__((ext_vector_type(8)));
typedef float f32x16 __attribute__((ext_vector_type(16)));
typedef float f32x4  __attribute__((ext_vector_type(4)));

#define NODES  2
#define LAYERS 4
#define HD     256
#define MTILE  128
#define QBYTES 32768              // one K-quarter of one layer: 256 n x 64 k x 2B
#define NQ     (NODES*LAYERS*4)   // 32 staged quarters

__device__ __forceinline__ unsigned short f2bf(float f) {  // RNE f32->bf16
  unsigned u = __float_as_uint(f);
  u += 0x7fffu + ((u >> 16) & 1u);
  return (unsigned short)(u >> 16);
}
__device__ __forceinline__ float bf2f(unsigned short s) {
  return __uint_as_float(((unsigned)s) << 16);
}
__device__ __forceinline__ float elu1(float v) {
  return v > 0.0f ? v : (__expf(v) - 1.0f);
}
__device__ __forceinline__ f32x16 zero16() {
  f32x16 z;
#pragma unroll
  for (int i = 0; i < 16; ++i) z[i] = 0.0f;
  return z;
}

#define GLOAD_LDS16(gsrc, ldst)                                                        \
  __builtin_amdgcn_global_load_lds(                                                    \
      (const __attribute__((address_space(1))) unsigned int*)(gsrc),                   \
      (__attribute__((address_space(3))) unsigned int*)(ldst), 16, 0, 0)

// ------------- weight conversion: fp32 w_hid -> bf16, transposed (W^T[n][k]),
// ------------- split in K-quarters, XOR-pre-swizzled so a LINEAR global->LDS copy
// ------------- produces the swizzled LDS image (rule #21: both-sides-or-neither).
__global__ __launch_bounds__(256) void convw_kernel(const float* __restrict__ w_hid,
                                                    unsigned short* __restrict__ blob) {
  int e = blockIdx.x * 256 + threadIdx.x;   // 0 .. 2*4*256*256-1
  int nl = e >> 16;                          // node*4+layer (0..7)
  int k  = (e >> 8) & 255;
  int n  = e & 255;
  float v = w_hid[(nl * 256 + k) * 256 + n];
  int qq = k >> 6, kq = k & 63;
  unsigned boff = ((unsigned)(nl * 4 + qq) << 15)       // quarter block base
                + ((unsigned)n << 7)                    // row n, 128B per row
                + (((unsigned)(kq << 1)) ^ ((unsigned)((n & 7) << 4)));
  blob[boff >> 1] = f2bf(v);
}

// ---------------- main fused kernel ----------------
// 8 waves: wave = (mg in 0..1) x (ng in 0..3); wave tile = 64 n x 64 m.
// mfma(A=W^T frag, B=h^T frag): D = h_new^T -> lane holds row m = lane&31,
// 16 n's per frag in quads -> ds_write_b64 packed epilogue.
__global__ __launch_bounds__(512, 2) void nld_kernel(
    const float* __restrict__ uv, const float* __restrict__ w_in,
    const float* __restrict__ b_in, const float* __restrict__ b_hid,
    const float* __restrict__ w_out, const float* __restrict__ b_out,
    const unsigned short* __restrict__ blob, float* __restrict__ out, int nrows) {

  __shared__ __attribute__((aligned(16))) char  h_lds[MTILE * 512];      // 64KB bf16 [128][256], swz ^((m&31)<<4)
  __shared__ __attribute__((aligned(16))) char  w_sm[2][QBYTES];         // 64KB dbuf W quarter
  __shared__ __attribute__((aligned(16))) float x_lds[MTILE * 2];        // residual x, fp32
  __shared__ __attribute__((aligned(16))) float pw_in[NODES * 2 * HD];
  __shared__ __attribute__((aligned(16))) float pb_in[NODES * HD];
  __shared__ __attribute__((aligned(16))) float pw_out[NODES * HD * 2];
  __shared__ __attribute__((aligned(16))) float pb_hid[NODES * LAYERS * HD];
  __shared__ float pb_out[NODES * 2];

  const int t    = threadIdx.x;
  const int lane = t & 63;
  const int wv   = t >> 6;
  const int mg   = wv >> 2;      // 0..1  (m 64-block)
  const int ng   = wv & 3;       // 0..3  (n 64-block)
  const int l31  = lane & 31;
  const int g    = lane >> 5;
  const long row0 = (long)blockIdx.x * MTILE;

  auto stage = [&](int i) {      // issue one 32KB quarter into w_sm[i&1]
    const char* src = (const char*)blob + (size_t)i * QBYTES + t * 16;
    char* dst = &w_sm[i & 1][t * 16];
#pragma unroll
    for (int r = 0; r < 4; ++r) GLOAD_LDS16(src + r * 8192, dst + r * 8192);
  };

  stage(0);
  // small params -> LDS
  for (int i = t; i < NODES * 2 * HD; i += 512) { pw_in[i] = w_in[i]; pw_out[i] = w_out[i]; }
  for (int i = t; i < NODES * HD; i += 512) pb_in[i] = b_in[i];
  for (int i = t; i < NODES * LAYERS * HD; i += 512) pb_hid[i] = b_hid[i];
  if (t < NODES * 2) pb_out[t] = b_out[t];
  if (t < 256) {
    long idx = row0 * 2 + t;
    x_lds[t] = (idx < (long)nrows * 2) ? uv[idx] : 0.0f;
  }
  __syncthreads();

  // per-thread constant offsets
  const int mrow0 = 64 * mg + l31;            // h rows (B operand)
  const unsigned hb0 = (unsigned)(mrow0 * 512), hb1 = (unsigned)((mrow0 + 32) * 512);
  const unsigned hsw = (unsigned)(l31 << 4);  // (row&31)<<4, same for both rows
  const int nrow0 = 64 * ng + l31;            // W^T rows (A operand)
  const unsigned wb0 = (unsigned)(nrow0 * 128), wb1 = (unsigned)((nrow0 + 32) * 128);
  const unsigned wsw = (unsigned)((l31 & 7) << 4);

  auto epi = [&](const f32x16& a, int nf, int mf, int nd, int ly) {
    int m = 64 * mg + 32 * mf + l31;
    unsigned hb = (unsigned)(m * 512), sw = (unsigned)((m & 31) << 4);
    int nb = 64 * ng + 32 * nf;
    const float* bias = &pb_hid[(nd * LAYERS + ly) * HD + nb];
#pragma unroll
    for (int q = 0; q < 4; ++q) {
      int n4 = 8 * q + 4 * g;                 // quad base within 32-n frag
      f32x4 bq = *(const f32x4*)(bias + n4);
      float v0 = elu1(a[4 * q + 0] + bq[0]);
      float v1 = elu1(a[4 * q + 1] + bq[1]);
      float v2 = elu1(a[4 * q + 2] + bq[2]);
      float v3 = elu1(a[4 * q + 3] + bq[3]);
      uint2 pk;
      pk.x = (unsigned)f2bf(v0) | ((unsigned)f2bf(v1) << 16);
      pk.y = (unsigned)f2bf(v2) | ((unsigned)f2bf(v3) << 16);
      *(uint2*)(h_lds + hb + (((unsigned)(2 * (nb + n4))) ^ sw)) = pk;
    }
  };

  for (int nd = 0; nd < NODES; ++nd) {
    // ---- input layer: h = elu(x @ w_in + b_in), fp32 VALU, quantize once
    {
      int m = t & 127;
      int nb = (t >> 7) * 64;
      float x0 = x_lds[2 * m], x1 = x_lds[2 * m + 1];
      unsigned hb = (unsigned)(m * 512), sw = (unsigned)((m & 31) << 4);
#pragma unroll 4
      for (int c4 = 0; c4 < 64; c4 += 4) {
        int n = nb + c4;
        f32x4 w0 = *(const f32x4*)&pw_in[(nd * 2 + 0) * HD + n];
        f32x4 w1 = *(const f32x4*)&pw_in[(nd * 2 + 1) * HD + n];
        f32x4 bb = *(const f32x4*)&pb_in[nd * HD + n];
        float v0 = elu1(fmaf(x1, w1[0], fmaf(x0, w0[0], bb[0])));
        float v1 = elu1(fmaf(x1, w1[1], fmaf(x0, w0[1], bb[1])));
        float v2 = elu1(fmaf(x1, w1[2], fmaf(x0, w0[2], bb[2])));
        float v3 = elu1(fmaf(x1, w1[3], fmaf(x0, w0[3], bb[3])));
        uint2 pk;
        pk.x = (unsigned)f2bf(v0) | ((unsigned)f2bf(v1) << 16);
        pk.y = (unsigned)f2bf(v2) | ((unsigned)f2bf(v3) << 16);
        *(uint2*)(h_lds + hb + (((unsigned)(2 * n)) ^ sw)) = pk;
      }
    }

    // ---- 4 hidden layers, MFMA, K staged in quarters (prefetch depth 1)
    for (int ly = 0; ly < LAYERS; ++ly) {
      f32x16 acc00 = zero16(), acc01 = zero16(), acc10 = zero16(), acc11 = zero16();
      for (int qq = 0; qq < 4; ++qq) {
        int iq = (nd * LAYERS + ly) * 4 + qq;
        __syncthreads();                       // waits stage(iq); frees buf (iq+1)&1
        if (iq + 1 < NQ) stage(iq + 1);
        const char* wb = &w_sm[iq & 1][0];
#pragma unroll
        for (int ks = 0; ks < 4; ++ks) {
          unsigned ka = (unsigned)(128 * qq + 32 * ks + 16 * g);   // byte k-off in h row
          bf16x8 h0 = *(const bf16x8*)(h_lds + hb0 + (ka ^ hsw));
          bf16x8 h1 = *(const bf16x8*)(h_lds + hb1 + (ka ^ hsw));
          unsigned kb = (unsigned)(32 * ks + 16 * g);              // byte k-off in W row
          bf16x8 w0 = *(const bf16x8*)(wb + wb0 + (kb ^ wsw));
          bf16x8 w1 = *(const bf16x8*)(wb + wb1 + (kb ^ wsw));
          acc00 = __builtin_amdgcn_mfma_f32_32x32x16_bf16(w0, h0, acc00, 0, 0, 0);
          acc01 = __builtin_amdgcn_mfma_f32_32x32x16_bf16(w0, h1, acc01, 0, 0, 0);
          acc10 = __builtin_amdgcn_mfma_f32_32x32x16_bf16(w1, h0, acc10, 0, 0, 0);
          acc11 = __builtin_amdgcn_mfma_f32_32x32x16_bf16(w1, h1, acc11, 0, 0, 0);
        }
      }
      __syncthreads();                         // all waves done reading old h
      epi(acc00, 0, 0, nd, ly);
      epi(acc01, 0, 1, nd, ly);
      epi(acc10, 1, 0, nd, ly);
      epi(acc11, 1, 1, nd, ly);
    }
    __syncthreads();                           // epilogue writes visible

    // ---- output layer: x += h @ w_out + b_out (fp32 VALU dot, k split 8 ways)
    {
      int kr = t & 7, d = (t >> 3) & 1, m4 = t >> 4;
      int k0 = kr * 32;
      float wreg[32];
#pragma unroll
      for (int kk = 0; kk < 32; kk += 2) {
        f32x4 wq = *(const f32x4*)&pw_out[(nd * HD + k0 + kk) * 2];
        wreg[kk]     = d ? wq[1] : wq[0];
        wreg[kk + 1] = d ? wq[3] : wq[2];
      }
      float s0 = 0.f, s1 = 0.f, s2 = 0.f, s3 = 0.f;
#pragma unroll
      for (int i = 0; i < 4; ++i) {
        int m = 4 * m4 + i;
        unsigned hb = (unsigned)(m * 512), sw = (unsigned)((m & 31) << 4);
        float acc = 0.f;
#pragma unroll
        for (int k8 = 0; k8 < 32; k8 += 8) {
          bf16x8 hv = *(const bf16x8*)(h_lds + hb + (((unsigned)(2 * (k0 + k8))) ^ sw));
#pragma unroll
          for (int j = 0; j < 8; ++j)
            acc = fmaf(bf2f((unsigned short)hv[j]), wreg[k8 + j], acc);
        }
        if (i == 0) s0 = acc; else if (i == 1) s1 = acc; else if (i == 2) s2 = acc; else s3 = acc;
      }
      s0 += __shfl_xor(s0, 1); s0 += __shfl_xor(s0, 2); s0 += __shfl_xor(s0, 4);
      s1 += __shfl_xor(s1, 1); s1 += __shfl_xor(s1, 2); s1 += __shfl_xor(s1, 4);
      s2 += __shfl_xor(s2, 1); s2 += __shfl_xor(s2, 2); s2 += __shfl_xor(s2, 4);
      s3 += __shfl_xor(s3, 1); s3 += __shfl_xor(s3, 2); s3 += __shfl_xor(s3, 4);
      if (kr == 0) {
        float bo = pb_out[nd * 2 + d];
        x_lds[(4 * m4 + 0) * 2 + d] += s0 + bo;
        x_lds[(4 * m4 + 1) * 2 + d] += s1 + bo;
        x_lds[(4 * m4 + 2) * 2 + d] += s2 + bo;
        x_lds[(4 * m4 + 3) * 2 + d] += s3 + bo;
      }
    }
    __syncthreads();                           // x_lds updated
  }

  if (t < 256) {
    long idx = row0 * 2 + t;
    if (idx < (long)nrows * 2) out[idx] = x_lds[t];
  }
}

// ---------------- launcher ----------------
extern "C" void kernel_launch(void* const* d_in, const int* in_sizes, int n_in,
                              void* d_out, int out_size, void* d_ws, size_t ws_size,
                              hipStream_t stream) {
  const float* uv    = (const float*)d_in[0];
  const float* w_in  = (const float*)d_in[1];
  const float* b_in  = (const float*)d_in[2];
  const float* w_hid = (const float*)d_in[3];
  const float* b_hid = (const float*)d_in[4];
  const float* w_out = (const float*)d_in[5];
  const float* b_out = (const float*)d_in[6];
  unsigned short* blob = (unsigned short*)d_ws;   // 1 MB bf16 weight blob

  int whid_elems = in_sizes[3];                   // 524288
  convw_kernel<<<whid_elems / 256, 256, 0, stream>>>(w_hid, blob);

  int N = in_sizes[0] / 2;                        // 1048576 rows
  int grid = (N + MTILE - 1) / MTILE;             // 8192
  nld_kernel<<<grid, 512, 0, stream>>>(uv, w_in, b_in, b_hid, w_out, b_out,
                                       blob, (float*)d_out, N);
}

// Round 2
// 1290.186 us; speedup vs baseline: 1.3985x; 1.3985x over previous
//
#include <hip/hip_runtime.h>
#include <stdint.h>

// ---------------- types ----------------
typedef short bf16x8 __attribute__((ext_vector_type(8)));
typedef float f32x16 __attribute__((ext_vector_type(16)));
typedef float f32x4  __attribute__((ext_vector_type(4)));
typedef float f32x2  __attribute__((ext_vector_type(2)));

#define NODES  2
#define LAYERS 4
#define HD     256
#define MTILE  128                // rows per block = 4 waves x 32
#define QBYTES 32768              // one K-quarter of one layer: 256 n x 64 k x 2B
#define NQ     (NODES*LAYERS*4)   // 32 staged quarters

__device__ __forceinline__ unsigned short f2bf(float f) {  // RNE f32->bf16
  unsigned u = __float_as_uint(f);
  u += 0x7fffu + ((u >> 16) & 1u);
  return (unsigned short)(u >> 16);
}
__device__ __forceinline__ float bf2f(unsigned short s) {
  return __uint_as_float(((unsigned)s) << 16);
}
__device__ __forceinline__ float elu1(float v) {
  return v > 0.0f ? v : (__expf(v) - 1.0f);
}
__device__ __forceinline__ unsigned cvtpk(float lo, float hi) {  // low16=bf16(lo)
  unsigned r;
  asm("v_cvt_pk_bf16_f32 %0, %1, %2" : "=v"(r) : "v"(lo), "v"(hi));
  return r;
}
union U8 { bf16x8 v; unsigned u[4]; };

#define GLOAD_LDS16(gsrc, ldst)                                                        \
  __builtin_amdgcn_global_load_lds(                                                    \
      (const __attribute__((address_space(1))) unsigned int*)(gsrc),                   \
      (__attribute__((address_space(3))) unsigned int*)(ldst), 16, 0, 0)

// Blob layout: per (node,layer,quarter): 256 rows (n) x 128B. Within a row,
// k is sigma-permuted per 16-chunk (pos = 8g+i <-> k16 = 4g + (i&3) + 8*(i>>2))
// so that D-fragments feed the next layer's B operand with ZERO cross-lane ops.
// Bytes are XOR-swizzled by ((n&7)<<4) so linear global_load_lds + swizzled
// ds_read compose (both-sides rule).
__global__ __launch_bounds__(256) void convw_kernel(const float* __restrict__ w_hid,
                                                    unsigned short* __restrict__ blob) {
  int e = blockIdx.x * 256 + threadIdx.x;    // 0 .. 2*4*256*256-1
  int nl = e >> 16;                          // node*4+layer
  int k  = (e >> 8) & 255;
  int n  = e & 255;
  float v = w_hid[(nl * 256 + k) * 256 + n];
  int qq    = k >> 6;
  int c_loc = (k >> 4) & 3;                  // chunk within quarter
  int k16   = k & 15;
  int g     = (k16 >> 2) & 1;
  int i     = (k16 & 3) + ((k16 >> 3) << 2);
  int pos   = (c_loc << 4) + (g << 3) + i;   // element index within 64-wide row
  unsigned boff = ((unsigned)(nl * 4 + qq) << 15)
                + ((unsigned)n << 7)
                + (((unsigned)(pos << 1)) ^ ((unsigned)((n & 7) << 4)));
  blob[boff >> 1] = f2bf(v);
}

// ---------------- main fused kernel ----------------
// 4 waves x 32 rows; h lives in registers as B-fragments hb[16] (bf16x8 each,
// chunk c holds k = 16c + 4g + (i&3) + 8*(i>>2)). acc[8] f32x16 covers n=0..255.
__global__ __launch_bounds__(256, 2) void nld_kernel(
    const float* __restrict__ uv, const float* __restrict__ w_in,
    const float* __restrict__ b_in, const float* __restrict__ b_hid,
    const float* __restrict__ w_out, const float* __restrict__ b_out,
    const unsigned short* __restrict__ blob, float* __restrict__ out, int nrows) {

  __shared__ __attribute__((aligned(16))) char  w_sm[2][QBYTES];   // 64KB dbuf
  __shared__ __attribute__((aligned(16))) float pb_hid[NODES * LAYERS * HD]; // 8KB
  __shared__ __attribute__((aligned(16))) float pb_in[NODES * HD];           // 2KB

  const int t    = threadIdx.x;
  const int lane = t & 63;
  const int wv   = t >> 6;        // 0..3
  const int l31  = lane & 31;
  const int g    = lane >> 5;
  const long row = (long)blockIdx.x * MTILE + wv * 32 + l31;

  auto stage = [&](int i) {       // issue one 32KB quarter into w_sm[i&1]
    const char* src = (const char*)blob + (size_t)i * QBYTES + t * 16;
    char* dst = &w_sm[i & 1][t * 16];
#pragma unroll
    for (int r = 0; r < 8; ++r) GLOAD_LDS16(src + r * 4096, dst + r * 4096);
  };

  stage(0);
  for (int i = t; i < NODES * LAYERS * HD; i += 256) pb_hid[i] = b_hid[i];
  for (int i = t; i < NODES * HD; i += 256) pb_in[i] = b_in[i];

  float x0 = 0.0f, x1 = 0.0f;
  if (row < nrows) { f32x2 u = *(const f32x2*)(uv + row * 2); x0 = u[0]; x1 = u[1]; }
  __syncthreads();   // stage(0) + param writes visible

  bf16x8 hb[16];
  const unsigned swz = (unsigned)((l31 & 7) << 4);
  const unsigned rowb = (unsigned)(l31 * 128);

  for (int nd = 0; nd < NODES; ++nd) {
    // ---- input layer: build hb directly (lane computes exactly its k-set)
    {
      const float* wi0 = w_in + nd * 2 * HD;        // d=0 row
      const float* wi1 = wi0 + HD;                  // d=1 row
      const float* bi  = &pb_in[nd * HD];
#pragma unroll
      for (int c = 0; c < 16; ++c) {
        int kb = 16 * c + 4 * g;
        f32x4 a0 = *(const f32x4*)(wi0 + kb);
        f32x4 a1 = *(const f32x4*)(wi0 + kb + 8);
        f32x4 c0 = *(const f32x4*)(wi1 + kb);
        f32x4 c1 = *(const f32x4*)(wi1 + kb + 8);
        f32x4 e0 = *(const f32x4*)(bi + kb);
        f32x4 e1 = *(const f32x4*)(bi + kb + 8);
        float v0 = elu1(fmaf(x1, c0[0], fmaf(x0, a0[0], e0[0])));
        float v1 = elu1(fmaf(x1, c0[1], fmaf(x0, a0[1], e0[1])));
        float v2 = elu1(fmaf(x1, c0[2], fmaf(x0, a0[2], e0[2])));
        float v3 = elu1(fmaf(x1, c0[3], fmaf(x0, a0[3], e0[3])));
        float v4 = elu1(fmaf(x1, c1[0], fmaf(x0, a1[0], e1[0])));
        float v5 = elu1(fmaf(x1, c1[1], fmaf(x0, a1[1], e1[1])));
        float v6 = elu1(fmaf(x1, c1[2], fmaf(x0, a1[2], e1[2])));
        float v7 = elu1(fmaf(x1, c1[3], fmaf(x0, a1[3], e1[3])));
        U8 p;
        p.u[0] = cvtpk(v0, v1); p.u[1] = cvtpk(v2, v3);
        p.u[2] = cvtpk(v4, v5); p.u[3] = cvtpk(v6, v7);
        hb[c] = p.v;
      }
    }

    // ---- 4 hidden layers: MFMA with register-resident h
    for (int ly = 0; ly < LAYERS; ++ly) {
      f32x16 acc[8];
#pragma unroll
      for (int nf = 0; nf < 8; ++nf)
#pragma unroll
        for (int j = 0; j < 16; ++j) acc[nf][j] = 0.0f;

      const int iq0 = (nd * LAYERS + ly) * 4;
#pragma unroll
      for (int qq = 0; qq < 4; ++qq) {
        int iq = iq0 + qq;
        __syncthreads();                       // stage(iq) done; buf (iq+1)&1 free
        if (iq + 1 < NQ) stage(iq + 1);
        const char* wbuf = &w_sm[iq & 1][0];
        __builtin_amdgcn_s_setprio(1);
#pragma unroll
        for (int kc = 0; kc < 4; ++kc) {
          unsigned koff = (unsigned)(32 * kc + 16 * g) ^ swz;
#pragma unroll
          for (int nf = 0; nf < 8; ++nf) {
            bf16x8 wf = *(const bf16x8*)(wbuf + 4096 * nf + rowb + koff);
            acc[nf] = __builtin_amdgcn_mfma_f32_32x32x16_bf16(wf, hb[4 * qq + kc],
                                                              acc[nf], 0, 0, 0);
          }
        }
        __builtin_amdgcn_s_setprio(0);
      }

      // ---- transform: acc -> hb (bias, ELU, cvt_pk) — no cross-lane ops
      const float* bl = &pb_hid[(nd * LAYERS + ly) * HD];
#pragma unroll
      for (int nf = 0; nf < 8; ++nf) {
        int nb = 32 * nf + 4 * g;
        f32x4 b0 = *(const f32x4*)(bl + nb);
        f32x4 b1 = *(const f32x4*)(bl + nb + 8);
        f32x4 b2 = *(const f32x4*)(bl + nb + 16);
        f32x4 b3 = *(const f32x4*)(bl + nb + 24);
        float e[16];
#pragma unroll
        for (int j = 0; j < 4; ++j) {
          e[j]      = elu1(acc[nf][j]      + b0[j]);
          e[4 + j]  = elu1(acc[nf][4 + j]  + b1[j]);
          e[8 + j]  = elu1(acc[nf][8 + j]  + b2[j]);
          e[12 + j] = elu1(acc[nf][12 + j] + b3[j]);
        }
        U8 p, q;
        p.u[0] = cvtpk(e[0],  e[1]);  p.u[1] = cvtpk(e[2],  e[3]);
        p.u[2] = cvtpk(e[4],  e[5]);  p.u[3] = cvtpk(e[6],  e[7]);
        q.u[0] = cvtpk(e[8],  e[9]);  q.u[1] = cvtpk(e[10], e[11]);
        q.u[2] = cvtpk(e[12], e[13]); q.u[3] = cvtpk(e[14], e[15]);
        hb[2 * nf]     = p.v;
        hb[2 * nf + 1] = q.v;
      }
    }

    // ---- output layer: x += h @ w_out + b_out (reg h, broadcast w_out loads)
    {
      const float* wo = w_out + nd * HD * 2;
      float s0 = 0.0f, s1 = 0.0f;
#pragma unroll
      for (int c = 0; c < 16; ++c) {
        int kb = 16 * c + 4 * g;
        f32x4 wA0 = *(const f32x4*)(wo + kb * 2);           // k=kb..kb+1, d0 d1
        f32x4 wA1 = *(const f32x4*)(wo + kb * 2 + 4);       // k=kb+2..kb+3
        f32x4 wB0 = *(const f32x4*)(wo + (kb + 8) * 2);
        f32x4 wB1 = *(const f32x4*)(wo + (kb + 8) * 2 + 4);
        bf16x8 hv = hb[c];
        float f0 = bf2f((unsigned short)hv[0]), f1 = bf2f((unsigned short)hv[1]);
        float f2 = bf2f((unsigned short)hv[2]), f3 = bf2f((unsigned short)hv[3]);
        float f4 = bf2f((unsigned short)hv[4]), f5 = bf2f((unsigned short)hv[5]);
        float f6 = bf2f((unsigned short)hv[6]), f7 = bf2f((unsigned short)hv[7]);
        s0 = fmaf(f0, wA0[0], s0); s1 = fmaf(f0, wA0[1], s1);
        s0 = fmaf(f1, wA0[2], s0); s1 = fmaf(f1, wA0[3], s1);
        s0 = fmaf(f2, wA1[0], s0); s1 = fmaf(f2, wA1[1], s1);
        s0 = fmaf(f3, wA1[2], s0); s1 = fmaf(f3, wA1[3], s1);
        s0 = fmaf(f4, wB0[0], s0); s1 = fmaf(f4, wB0[1], s1);
        s0 = fmaf(f5, wB0[2], s0); s1 = fmaf(f5, wB0[3], s1);
        s0 = fmaf(f6, wB1[0], s0); s1 = fmaf(f6, wB1[1], s1);
        s0 = fmaf(f7, wB1[2], s0); s1 = fmaf(f7, wB1[3], s1);
      }
      s0 += __shfl_xor(s0, 32);
      s1 += __shfl_xor(s1, 32);
      x0 += s0 + b_out[nd * 2 + 0];
      x1 += s1 + b_out[nd * 2 + 1];
    }
  }

  if (row < nrows && g == 0) {
    f32x2 r; r[0] = x0; r[1] = x1;
    *(f32x2*)(out + row * 2) = r;
  }
}

// ---------------- launcher ----------------
extern "C" void kernel_launch(void* const* d_in, const int* in_sizes, int n_in,
                              void* d_out, int out_size, void* d_ws, size_t ws_size,
                              hipStream_t stream) {
  const float* uv    = (const float*)d_in[0];
  const float* w_in  = (const float*)d_in[1];
  const float* b_in  = (const float*)d_in[2];
  const float* w_hid = (const float*)d_in[3];
  const float* b_hid = (const float*)d_in[4];
  const float* w_out = (const float*)d_in[5];
  const float* b_out = (const float*)d_in[6];
  unsigned short* blob = (unsigned short*)d_ws;   // 1 MB bf16 sigma-permuted blob

  int whid_elems = in_sizes[3];                   // 524288
  convw_kernel<<<whid_elems / 256, 256, 0, stream>>>(w_hid, blob);

  int N = in_sizes[0] / 2;                        // 1048576 rows
  int grid = (N + MTILE - 1) / MTILE;             // 8192
  nld_kernel<<<grid, 256, 0, stream>>>(uv, w_in, b_in, b_hid, w_out, b_out,
                                       blob, (float*)d_out, N);
}

// Round 3
// 1245.905 us; speedup vs baseline: 1.4482x; 1.0355x over previous
//
#include <hip/hip_runtime.h>
#include <stdint.h>

// ---------------- types ----------------
typedef short bf16x8 __attribute__((ext_vector_type(8)));
typedef float f32x16 __attribute__((ext_vector_type(16)));
typedef float f32x4  __attribute__((ext_vector_type(4)));
typedef float f32x2  __attribute__((ext_vector_type(2)));

#define NODES  2
#define LAYERS 4
#define HD     256
#define MTILE  128                // rows per block = 4 waves x 32
#define QBYTES 32768              // one K-quarter of one layer: 256 n x 64 k x 2B
#define NQ     (NODES*LAYERS*4)   // 32 staged quarters

__device__ __forceinline__ unsigned short f2bf(float f) {  // RNE f32->bf16
  unsigned u = __float_as_uint(f);
  u += 0x7fffu + ((u >> 16) & 1u);
  return (unsigned short)(u >> 16);
}
__device__ __forceinline__ float bf2f(unsigned short s) {
  return __uint_as_float(((unsigned)s) << 16);
}
__device__ __forceinline__ float elu1(float v) {
  return v > 0.0f ? v : (__expf(v) - 1.0f);
}
__device__ __forceinline__ unsigned cvtpk(float lo, float hi) {  // low16=bf16(lo)
  unsigned r;
  asm("v_cvt_pk_bf16_f32 %0, %1, %2" : "=v"(r) : "v"(lo), "v"(hi));
  return r;
}
union U8 { bf16x8 v; unsigned u[4]; };

#define GLOAD_LDS16(gsrc, ldst)                                                        \
  __builtin_amdgcn_global_load_lds(                                                    \
      (const __attribute__((address_space(1))) unsigned int*)(gsrc),                   \
      (__attribute__((address_space(3))) unsigned int*)(ldst), 16, 0, 0)

// Blob layout (conflict-free, zero-swizzle): per (node,layer) 4 quarters of 32KB.
// Quarter = [kc(4)][g(2)][nf(8)][l31(32)] x 16B fragments. For a fixed
// (kc,g,nf) the 32 lanes of a half-wave read 32 CONSECUTIVE 16B chunks
// (same pattern as the linear global_load_lds dest order -> 0 bank conflicts),
// and all 32 ds_read_b128 of a quarter are immediate offsets off one base.
// Within a fragment, element i holds k = 64*qq + 16*kc + 4*g + (i&3) + 8*(i>>2)
// (the sigma permutation that makes D-frags feed B-frags with no cross-lane ops).
__global__ __launch_bounds__(256) void convw_kernel(const float* __restrict__ w_hid,
                                                    unsigned short* __restrict__ blob) {
  int e = blockIdx.x * 256 + threadIdx.x;    // 0 .. 2*4*256*256-1
  int nl = e >> 16;                          // node*4+layer
  int k  = (e >> 8) & 255;
  int n  = e & 255;
  float v = w_hid[(nl * 256 + k) * 256 + n];
  int qq  = k >> 6;
  int kc  = (k >> 4) & 3;
  int k16 = k & 15;
  int g   = (k16 >> 2) & 1;
  int i   = (k16 & 3) | ((k16 >> 3) << 2);
  int nf  = n >> 5, l31 = n & 31;
  unsigned boff = ((unsigned)(nl * 4 + qq) << 15)
                + ((unsigned)kc << 13) + ((unsigned)g << 12)
                + ((unsigned)nf << 9) + ((unsigned)l31 << 4) + ((unsigned)i << 1);
  blob[boff >> 1] = f2bf(v);
}

// ---------------- main fused kernel ----------------
// 4 waves x 32 rows; h register-resident as B-frags hb[16]; acc[8] f32x16
// covers n=0..255, initialized with the bias (D-layout makes bias lane-uniform
// per register index within each 32-lane half).
__global__ __launch_bounds__(256, 2) void nld_kernel(
    const float* __restrict__ uv, const float* __restrict__ w_in,
    const float* __restrict__ b_in, const float* __restrict__ b_hid,
    const float* __restrict__ w_out, const float* __restrict__ b_out,
    const unsigned short* __restrict__ blob, float* __restrict__ out, int nrows) {

  __shared__ __attribute__((aligned(16))) char  w_sm[2][QBYTES];   // 64KB dbuf
  __shared__ __attribute__((aligned(16))) float pb_hid[NODES * LAYERS * HD]; // 8KB
  __shared__ __attribute__((aligned(16))) float pb_in[NODES * HD];           // 2KB

  const int t    = threadIdx.x;
  const int lane = t & 63;
  const int wv   = t >> 6;        // 0..3
  const int l31  = lane & 31;
  const int g    = lane >> 5;
  const long row = (long)blockIdx.x * MTILE + wv * 32 + l31;

  auto stage = [&](int i) {       // issue one 32KB quarter into w_sm[i&1]
    const char* src = (const char*)blob + (size_t)i * QBYTES + t * 16;
    char* dst = &w_sm[i & 1][t * 16];
#pragma unroll
    for (int r = 0; r < 8; ++r) GLOAD_LDS16(src + r * 4096, dst + r * 4096);
  };

  stage(0);
  for (int i = t; i < NODES * LAYERS * HD; i += 256) pb_hid[i] = b_hid[i];
  for (int i = t; i < NODES * HD; i += 256) pb_in[i] = b_in[i];

  float x0 = 0.0f, x1 = 0.0f;
  if (row < nrows) { f32x2 u = *(const f32x2*)(uv + row * 2); x0 = u[0]; x1 = u[1]; }
  __syncthreads();   // stage(0) + param writes visible

  bf16x8 hb[16];
  // per-lane fragment base within a quarter: [g][..][l31] -> g*4096 + l31*16
  const unsigned fbase = (unsigned)(g * 4096 + l31 * 16);
  const char* wq0 = &w_sm[0][0];
  const char* wq1 = &w_sm[1][0];

  for (int nd = 0; nd < NODES; ++nd) {
    // ---- input layer: build hb directly (lane computes exactly its k-set)
    {
      const float* wi0 = w_in + nd * 2 * HD;        // d=0 row
      const float* wi1 = wi0 + HD;                  // d=1 row
      const float* bi  = &pb_in[nd * HD];
#pragma unroll
      for (int c = 0; c < 16; ++c) {
        int kb = 16 * c + 4 * g;
        f32x4 a0 = *(const f32x4*)(wi0 + kb);
        f32x4 a1 = *(const f32x4*)(wi0 + kb + 8);
        f32x4 c0 = *(const f32x4*)(wi1 + kb);
        f32x4 c1 = *(const f32x4*)(wi1 + kb + 8);
        f32x4 e0 = *(const f32x4*)(bi + kb);
        f32x4 e1 = *(const f32x4*)(bi + kb + 8);
        float v0 = elu1(fmaf(x1, c0[0], fmaf(x0, a0[0], e0[0])));
        float v1 = elu1(fmaf(x1, c0[1], fmaf(x0, a0[1], e0[1])));
        float v2 = elu1(fmaf(x1, c0[2], fmaf(x0, a0[2], e0[2])));
        float v3 = elu1(fmaf(x1, c0[3], fmaf(x0, a0[3], e0[3])));
        float v4 = elu1(fmaf(x1, c1[0], fmaf(x0, a1[0], e1[0])));
        float v5 = elu1(fmaf(x1, c1[1], fmaf(x0, a1[1], e1[1])));
        float v6 = elu1(fmaf(x1, c1[2], fmaf(x0, a1[2], e1[2])));
        float v7 = elu1(fmaf(x1, c1[3], fmaf(x0, a1[3], e1[3])));
        U8 p;
        p.u[0] = cvtpk(v0, v1); p.u[1] = cvtpk(v2, v3);
        p.u[2] = cvtpk(v4, v5); p.u[3] = cvtpk(v6, v7);
        hb[c] = p.v;
      }
    }

    // ---- 4 hidden layers: MFMA with register-resident h
    for (int ly = 0; ly < LAYERS; ++ly) {
      // acc init = bias (saves the bias-add pass in the transform)
      const float* bl = &pb_hid[(nd * LAYERS + ly) * HD];
      f32x16 acc[8];
#pragma unroll
      for (int nf = 0; nf < 8; ++nf) {
        int nb = 32 * nf + 4 * g;
        f32x4 b0 = *(const f32x4*)(bl + nb);
        f32x4 b1 = *(const f32x4*)(bl + nb + 8);
        f32x4 b2 = *(const f32x4*)(bl + nb + 16);
        f32x4 b3 = *(const f32x4*)(bl + nb + 24);
#pragma unroll
        for (int j = 0; j < 4; ++j) {
          acc[nf][j]      = b0[j];
          acc[nf][4 + j]  = b1[j];
          acc[nf][8 + j]  = b2[j];
          acc[nf][12 + j] = b3[j];
        }
      }

      const int iq0 = (nd * LAYERS + ly) * 4;
#pragma unroll
      for (int qq = 0; qq < 4; ++qq) {
        int iq = iq0 + qq;
        __syncthreads();                       // stage(iq) done; buf (iq+1)&1 free
        if (iq + 1 < NQ) stage(iq + 1);
        const char* wbuf = ((iq & 1) ? wq1 : wq0) + fbase;
        __builtin_amdgcn_s_setprio(1);
#pragma unroll
        for (int kc = 0; kc < 4; ++kc) {
#pragma unroll
          for (int nf = 0; nf < 8; ++nf) {
            bf16x8 wf = *(const bf16x8*)(wbuf + kc * 8192 + nf * 512);
            acc[nf] = __builtin_amdgcn_mfma_f32_32x32x16_bf16(wf, hb[4 * qq + kc],
                                                              acc[nf], 0, 0, 0);
          }
        }
        __builtin_amdgcn_s_setprio(0);
      }

      // ---- transform: acc -> hb (ELU + cvt_pk) — bias already in acc
#pragma unroll
      for (int nf = 0; nf < 8; ++nf) {
        float e[16];
#pragma unroll
        for (int j = 0; j < 16; ++j) e[j] = elu1(acc[nf][j]);
        U8 p, q;
        p.u[0] = cvtpk(e[0],  e[1]);  p.u[1] = cvtpk(e[2],  e[3]);
        p.u[2] = cvtpk(e[4],  e[5]);  p.u[3] = cvtpk(e[6],  e[7]);
        q.u[0] = cvtpk(e[8],  e[9]);  q.u[1] = cvtpk(e[10], e[11]);
        q.u[2] = cvtpk(e[12], e[13]); q.u[3] = cvtpk(e[14], e[15]);
        hb[2 * nf]     = p.v;
        hb[2 * nf + 1] = q.v;
      }
    }

    // ---- output layer: x += h @ w_out + b_out (reg h, broadcast w_out loads)
    {
      const float* wo = w_out + nd * HD * 2;
      float s0 = 0.0f, s1 = 0.0f;
#pragma unroll
      for (int c = 0; c < 16; ++c) {
        int kb = 16 * c + 4 * g;
        f32x4 wA0 = *(const f32x4*)(wo + kb * 2);           // k=kb..kb+1, d0 d1
        f32x4 wA1 = *(const f32x4*)(wo + kb * 2 + 4);       // k=kb+2..kb+3
        f32x4 wB0 = *(const f32x4*)(wo + (kb + 8) * 2);
        f32x4 wB1 = *(const f32x4*)(wo + (kb + 8) * 2 + 4);
        bf16x8 hv = hb[c];
        float f0 = bf2f((unsigned short)hv[0]), f1 = bf2f((unsigned short)hv[1]);
        float f2 = bf2f((unsigned short)hv[2]), f3 = bf2f((unsigned short)hv[3]);
        float f4 = bf2f((unsigned short)hv[4]), f5 = bf2f((unsigned short)hv[5]);
        float f6 = bf2f((unsigned short)hv[6]), f7 = bf2f((unsigned short)hv[7]);
        s0 = fmaf(f0, wA0[0], s0); s1 = fmaf(f0, wA0[1], s1);
        s0 = fmaf(f1, wA0[2], s0); s1 = fmaf(f1, wA0[3], s1);
        s0 = fmaf(f2, wA1[0], s0); s1 = fmaf(f2, wA1[1], s1);
        s0 = fmaf(f3, wA1[2], s0); s1 = fmaf(f3, wA1[3], s1);
        s0 = fmaf(f4, wB0[0], s0); s1 = fmaf(f4, wB0[1], s1);
        s0 = fmaf(f5, wB0[2], s0); s1 = fmaf(f5, wB0[3], s1);
        s0 = fmaf(f6, wB1[0], s0); s1 = fmaf(f6, wB1[1], s1);
        s0 = fmaf(f7, wB1[2], s0); s1 = fmaf(f7, wB1[3], s1);
      }
      s0 += __shfl_xor(s0, 32);
      s1 += __shfl_xor(s1, 32);
      x0 += s0 + b_out[nd * 2 + 0];
      x1 += s1 + b_out[nd * 2 + 1];
    }
  }

  if (row < nrows && g == 0) {
    f32x2 r; r[0] = x0; r[1] = x1;
    *(f32x2*)(out + row * 2) = r;
  }
}

// ---------------- launcher ----------------
extern "C" void kernel_launch(void* const* d_in, const int* in_sizes, int n_in,
                              void* d_out, int out_size, void* d_ws, size_t ws_size,
                              hipStream_t stream) {
  const float* uv    = (const float*)d_in[0];
  const float* w_in  = (const float*)d_in[1];
  const float* b_in  = (const float*)d_in[2];
  const float* w_hid = (const float*)d_in[3];
  const float* b_hid = (const float*)d_in[4];
  const float* w_out = (const float*)d_in[5];
  const float* b_out = (const float*)d_in[6];
  unsigned short* blob = (unsigned short*)d_ws;   // 1 MB bf16 permuted blob

  int whid_elems = in_sizes[3];                   // 524288
  convw_kernel<<<whid_elems / 256, 256, 0, stream>>>(w_hid, blob);

  int N = in_sizes[0] / 2;                        // 1048576 rows
  int grid = (N + MTILE - 1) / MTILE;             // 8192
  nld_kernel<<<grid, 256, 0, stream>>>(uv, w_in, b_in, b_hid, w_out, b_out,
                                       blob, (float*)d_out, N);
}